// Round 3
// baseline (388.253 us; speedup 1.0000x reference)
//
#include <hip/hip_runtime.h>

typedef __attribute__((ext_vector_type(4))) float f32x4;
typedef __attribute__((ext_vector_type(8))) _Float16 f16x8;
typedef __attribute__((ext_vector_type(4))) _Float16 f16x4;

__device__ __forceinline__ void gload_lds16(const void* g, void* l) {
  __builtin_amdgcn_global_load_lds((__attribute__((address_space(1))) void*)(g),
                                   (__attribute__((address_space(3))) void*)(l), 16, 0, 0);
}

// ---------------- cast fp32 -> fp16 ----------------
__global__ __launch_bounds__(256) void cast_f32_f16(const float* __restrict__ x,
                                                    _Float16* __restrict__ y, int n) {
  int i = (blockIdx.x * 256 + threadIdx.x) * 4;
  if (i < n) {
    float4 v = *(const float4*)(x + i);
    f16x4 o = { (_Float16)v.x, (_Float16)v.y, (_Float16)v.z, (_Float16)v.w };
    *(f16x4*)(y + i) = o;
  }
}

// ---- transpose+cast weights: W[2048][2048] f32 (k-major) -> Wt[n][k] f16 ----
__global__ __launch_bounds__(256) void wtrans(const float* __restrict__ W0, const float* __restrict__ W1,
                                              const float* __restrict__ W2, const float* __restrict__ W3,
                                              _Float16* __restrict__ out) {
  const float* W = blockIdx.z == 0 ? W0 : blockIdx.z == 1 ? W1 : blockIdx.z == 2 ? W2 : W3;
  _Float16* Wt = out + (size_t)blockIdx.z * (2048u * 2048u);
  __shared__ _Float16 tile[64][65];
  const int tid = threadIdx.x;
  const int k0 = blockIdx.y * 64, n0 = blockIdx.x * 64;
  #pragma unroll
  for (int p = 0; p < 4; ++p) {
    int o = p * 256 + tid, r = o >> 4, c = o & 15;
    float4 v = *(const float4*)(W + (size_t)(k0 + r) * 2048 + n0 + c * 4);
    tile[r][c * 4 + 0] = (_Float16)v.x;
    tile[r][c * 4 + 1] = (_Float16)v.y;
    tile[r][c * 4 + 2] = (_Float16)v.z;
    tile[r][c * 4 + 3] = (_Float16)v.w;
  }
  __syncthreads();
  #pragma unroll
  for (int p = 0; p < 2; ++p) {
    int o = p * 256 + tid, nl = o >> 3, c = o & 7;
    f16x8 u;
    #pragma unroll
    for (int i = 0; i < 8; ++i) u[i] = tile[c * 8 + i][nl];
    *(f16x8*)(Wt + (size_t)(n0 + nl) * 2048 + k0 + c * 8) = u;
  }
}

// ---- transpose V[b*2048+s][h*128+d] -> Vt[(b*16+h)*128+d][s] (f16) ----
__global__ __launch_bounds__(256) void vtrans(const _Float16* __restrict__ V, _Float16* __restrict__ Vt) {
  const int s0 = blockIdx.x * 64, d0 = blockIdx.y * 64, bh = blockIdx.z;
  const int b = bh >> 4, h = bh & 15;
  __shared__ _Float16 tile[64][65];
  const int tid = threadIdx.x;
  #pragma unroll
  for (int p = 0; p < 2; ++p) {
    int o = p * 256 + tid, sl = o >> 3, c = o & 7;
    f16x8 v = *(const f16x8*)(V + (size_t)(b * 2048 + s0 + sl) * 2048 + h * 128 + d0 + c * 8);
    #pragma unroll
    for (int i = 0; i < 8; ++i) tile[sl][c * 8 + i] = v[i];
  }
  __syncthreads();
  #pragma unroll
  for (int p = 0; p < 2; ++p) {
    int o = p * 256 + tid, dl = o >> 3, c = o & 7;
    f16x8 u;
    #pragma unroll
    for (int i = 0; i < 8; ++i) u[i] = tile[c * 8 + i][dl];
    *(f16x8*)(Vt + (size_t)(bh * 128 + d0 + dl) * 2048 + s0 + c * 8) = u;
  }
}

// ---- m97-style GEMM: C[M][N] = A[M][K] * Bt[N][K]^T (unchanged from round 2) ----
template <typename OutT>
__global__ __launch_bounds__(256) void gemm_bt(const _Float16* __restrict__ A,
                                               const _Float16* __restrict__ Bt,
                                               OutT* __restrict__ C,
                                               int K, int N, size_t zsB, size_t zsC) {
  Bt += (size_t)blockIdx.z * zsB;
  C  += (size_t)blockIdx.z * zsC;
  __shared__ _Float16 As[128 * 32];
  __shared__ _Float16 Bs[128 * 32];
  const int tid = threadIdx.x;
  const int m0 = blockIdx.y * 128, n0 = blockIdx.x * 128;
  const int lane = tid & 63, w = tid >> 6, l16 = lane & 15, quad = lane >> 4;
  const int wm = (w & 1) * 64, wn = (w >> 1) * 64;
  f32x4 acc[4][4];
  #pragma unroll
  for (int i = 0; i < 4; ++i)
    #pragma unroll
    for (int j = 0; j < 4; ++j) acc[i][j] = (f32x4){0.f, 0.f, 0.f, 0.f};

  const int r0 = tid >> 2;
  const int c0 = ((tid & 3) ^ ((r0 >> 1) & 3)) * 8;
  const int swz = (quad ^ ((l16 >> 1) & 3)) * 8;

  for (int k0 = 0; k0 < K; k0 += 32) {
    __syncthreads();
    #pragma unroll
    for (int p = 0; p < 2; ++p) {
      int r = p * 64 + r0;
      gload_lds16(A  + (size_t)(m0 + r) * K + k0 + c0, (char*)As + (p * 256 + tid) * 16);
      gload_lds16(Bt + (size_t)(n0 + r) * K + k0 + c0, (char*)Bs + (p * 256 + tid) * 16);
    }
    __builtin_amdgcn_s_waitcnt(0);
    __syncthreads();
    f16x8 af[4], bfv[4];
    #pragma unroll
    for (int i = 0; i < 4; ++i) af[i]  = *(const f16x8*)(As + (wm + i * 16 + l16) * 32 + swz);
    #pragma unroll
    for (int j = 0; j < 4; ++j) bfv[j] = *(const f16x8*)(Bs + (wn + j * 16 + l16) * 32 + swz);
    #pragma unroll
    for (int i = 0; i < 4; ++i)
      #pragma unroll
      for (int j = 0; j < 4; ++j)
        acc[i][j] = __builtin_amdgcn_mfma_f32_16x16x32_f16(bfv[j], af[i], acc[i][j], 0, 0, 0);
  }
  #pragma unroll
  for (int i = 0; i < 4; ++i) {
    const size_t row = (size_t)(m0 + wm + i * 16 + l16);
    #pragma unroll
    for (int j = 0; j < 4; ++j) {
      const int col = n0 + wn + j * 16 + quad * 4;
      if constexpr (sizeof(OutT) == 2) {
        f16x4 o = { (_Float16)acc[i][j][0], (_Float16)acc[i][j][1],
                    (_Float16)acc[i][j][2], (_Float16)acc[i][j][3] };
        *(f16x4*)((_Float16*)C + row * N + col) = o;
      } else {
        *(f32x4*)((float*)C + row * N + col) = acc[i][j];
      }
    }
  }
}

// ---- block-sparse attention v2: WG = (q-tile of 128, head, batch).
// Waves 0-1 own q-block 2t, waves 2-3 own 2t+1 -> per-wave uniform block validity.
// Online softmax; S^T = K.Q^T; O^T += V^T.P^T with P^T straight from C-layout regs.
__global__ __launch_bounds__(256) void attn(const _Float16* __restrict__ Qg,
                                            const _Float16* __restrict__ Kg,
                                            const _Float16* __restrict__ Vtg,
                                            _Float16* __restrict__ Og) {
  const int t = blockIdx.x, h = blockIdx.y, b = blockIdx.z;
  __shared__ _Float16 Qs[128 * 128];  // 32 KB
  __shared__ _Float16 Ks[64 * 128];   // 16 KB
  __shared__ _Float16 Vs[128 * 64];   // 16 KB
  const int tid = threadIdx.x;
  const int lane = tid & 63, w = tid >> 6, l16 = lane & 15, quad = lane >> 4;
  const int qbw = 2 * t + (w >> 1);   // this wave's q-block
  const char* QsB = (const char*)Qs;
  const char* KsB = (const char*)Ks;
  const char* VsB = (const char*)Vs;

  // stage Q tile: 128 rows x 128 d, XOR-chunk swizzle
  #pragma unroll
  for (int p = 0; p < 8; ++p) {
    int o = p * 256 + tid, r = o >> 4, c = o & 15;
    gload_lds16(Qg + (size_t)(b * 2048 + t * 128 + r) * 2048 + h * 128 + ((c ^ (r & 15)) * 8),
                (char*)Qs + o * 16);
  }
  __builtin_amdgcn_s_waitcnt(0);
  __syncthreads();
  // Q fragments held in registers for the whole kernel (B-operand, q = n-dim)
  f16x8 qf[2][4];
  #pragma unroll
  for (int qc = 0; qc < 2; ++qc)
    #pragma unroll
    for (int ks = 0; ks < 4; ++ks)
      qf[qc][ks] = *(const f16x8*)(QsB + (w * 32 + qc * 16 + l16) * 256 +
                                   (((ks * 4 + quad) ^ l16) * 16));

  const float scale = 0.08838834764831845f;  // 1/sqrt(128)
  float m_[2] = {-1e30f, -1e30f}, l_[2] = {0.f, 0.f};
  f32x4 oacc[8][2];
  #pragma unroll
  for (int dt = 0; dt < 8; ++dt)
    #pragma unroll
    for (int qc = 0; qc < 2; ++qc) oacc[dt][qc] = (f32x4){0.f, 0.f, 0.f, 0.f};

  for (int jj = 0; jj < 6; ++jj) {
    const int j = 2 * t - 2 + jj;
    const int jc = j < 0 ? 0 : (j > 31 ? 31 : j);
    __syncthreads();  // previous compute done reading Ks/Vs
    #pragma unroll
    for (int p = 0; p < 4; ++p) {
      int o = p * 256 + tid, r = o >> 4, c = o & 15;
      gload_lds16(Kg + (size_t)(b * 2048 + jc * 64 + r) * 2048 + h * 128 + ((c ^ (r & 15)) * 8),
                  (char*)Ks + o * 16);
    }
    #pragma unroll
    for (int p = 0; p < 4; ++p) {
      int o = p * 256 + tid, d = o >> 3, c = o & 7;
      gload_lds16(Vtg + (size_t)((b * 16 + h) * 128 + d) * 2048 + jc * 64 + ((c ^ (d & 7)) * 8),
                  (char*)Vs + o * 16);
    }
    __builtin_amdgcn_s_waitcnt(0);
    __syncthreads();

    const bool valid = (j >= 0) && (j <= 31) && (j >= qbw - 2) && (j <= qbw + 2);
    if (valid) {
      // S^T = K . Q^T  (keys = m-dim, q = n-dim)
      f32x4 sc[4][2];
      #pragma unroll
      for (int kt = 0; kt < 4; ++kt)
        #pragma unroll
        for (int qc = 0; qc < 2; ++qc) sc[kt][qc] = (f32x4){0.f, 0.f, 0.f, 0.f};
      #pragma unroll
      for (int kt = 0; kt < 4; ++kt)
        #pragma unroll
        for (int ks = 0; ks < 4; ++ks) {
          f16x8 kf = *(const f16x8*)(KsB + (kt * 16 + l16) * 256 + (((ks * 4 + quad) ^ l16) * 16));
          #pragma unroll
          for (int qc = 0; qc < 2; ++qc)
            sc[kt][qc] = __builtin_amdgcn_mfma_f32_16x16x32_f16(kf, qf[qc][ks], sc[kt][qc], 0, 0, 0);
        }
      // online softmax per q-column (per qc)
      #pragma unroll
      for (int qc = 0; qc < 2; ++qc) {
        float mj = -1e30f;
        #pragma unroll
        for (int kt = 0; kt < 4; ++kt)
          #pragma unroll
          for (int r = 0; r < 4; ++r) {
            float v = sc[kt][qc][r] * scale;
            sc[kt][qc][r] = v;
            mj = fmaxf(mj, v);
          }
        mj = fmaxf(mj, __shfl_xor(mj, 16));
        mj = fmaxf(mj, __shfl_xor(mj, 32));
        const float mn = fmaxf(m_[qc], mj);
        const float alpha = __expf(m_[qc] - mn);
        float s_ = 0.f;
        #pragma unroll
        for (int kt = 0; kt < 4; ++kt)
          #pragma unroll
          for (int r = 0; r < 4; ++r) {
            float p = __expf(sc[kt][qc][r] - mn);
            sc[kt][qc][r] = p;
            s_ += p;
          }
        s_ += __shfl_xor(s_, 16);
        s_ += __shfl_xor(s_, 32);
        l_[qc] = l_[qc] * alpha + s_;
        m_[qc] = mn;
        #pragma unroll
        for (int dt = 0; dt < 8; ++dt) oacc[dt][qc] *= alpha;
      }
      // O^T += V^T . P^T  (P^T fragment == sc regs in B-operand layout for 16x16x16)
      #pragma unroll
      for (int kt = 0; kt < 4; ++kt) {
        f16x4 pb[2];
        #pragma unroll
        for (int qc = 0; qc < 2; ++qc)
          pb[qc] = (f16x4){ (_Float16)sc[kt][qc][0], (_Float16)sc[kt][qc][1],
                            (_Float16)sc[kt][qc][2], (_Float16)sc[kt][qc][3] };
        #pragma unroll
        for (int dt = 0; dt < 8; ++dt) {
          f16x4 vv = *(const f16x4*)(VsB + (dt * 16 + l16) * 128 +
                                     (((2 * kt + (quad >> 1)) ^ (l16 & 7)) * 16) + (quad & 1) * 8);
          #pragma unroll
          for (int qc = 0; qc < 2; ++qc)
            oacc[dt][qc] = __builtin_amdgcn_mfma_f32_16x16x16f16(vv, pb[qc], oacc[dt][qc], 0, 0, 0);
        }
      }
    }
  }

  // epilogue: O[q][d] = O^T / l
  #pragma unroll
  for (int qc = 0; qc < 2; ++qc) {
    const float pinv = 1.0f / l_[qc];
    const size_t orow = (size_t)(b * 2048 + t * 128 + w * 32 + qc * 16 + l16);
    #pragma unroll
    for (int dt = 0; dt < 8; ++dt) {
      f16x4 ov = { (_Float16)(oacc[dt][qc][0] * pinv), (_Float16)(oacc[dt][qc][1] * pinv),
                   (_Float16)(oacc[dt][qc][2] * pinv), (_Float16)(oacc[dt][qc][3] * pinv) };
      *(f16x4*)(Og + orow * 2048 + h * 128 + dt * 16 + quad * 4) = ov;
    }
  }
}

extern "C" void kernel_launch(void* const* d_in, const int* in_sizes, int n_in,
                              void* d_out, int out_size, void* d_ws, size_t ws_size,
                              hipStream_t stream) {
  const float* Hs = (const float*)d_in[0];
  const float* Wq = (const float*)d_in[1];
  const float* Wk = (const float*)d_in[2];
  const float* Wv = (const float*)d_in[3];
  const float* Wo = (const float*)d_in[4];
  _Float16* Hb  = (_Float16*)d_ws;          // H cast  [4096][2048]
  _Float16* Wt  = Hb  + 8388608;            // Wq/Wk/Wv/Wo^T  4 x [2048][2048]
  _Float16* Qb  = Wt  + 16777216;           // Q  [b*2048+s][h*128+d]
  _Float16* Kb  = Qb  + 8388608;            // K
  _Float16* Vb  = Kb  + 8388608;            // V
  _Float16* Vtb = Vb  + 8388608;            // V^T [(b*16+h)*128+d][s]
  _Float16* Ob  = Vtb + 8388608;            // attn out
  float* out = (float*)d_out;

  cast_f32_f16<<<8192, 256, 0, stream>>>(Hs, Hb, 8388608);
  wtrans<<<dim3(32, 32, 4), 256, 0, stream>>>(Wq, Wk, Wv, Wo, Wt);
  gemm_bt<_Float16><<<dim3(16, 32, 3), 256, 0, stream>>>(Hb, Wt, Qb, 2048, 2048,
                                                         (size_t)4194304, (size_t)8388608);
  vtrans<<<dim3(32, 2, 32), 256, 0, stream>>>(Vb, Vtb);
  attn<<<dim3(16, 16, 2), 256, 0, stream>>>(Qb, Kb, Vtb, Ob);
  gemm_bt<float><<<dim3(16, 32, 1), 256, 0, stream>>>(Ob, Wt + 3 * 4194304, out, 2048, 2048,
                                                      (size_t)0, (size_t)0);
}

// Round 4
// 363.831 us; speedup vs baseline: 1.0671x; 1.0671x over previous
//
#include <hip/hip_runtime.h>

typedef __attribute__((ext_vector_type(4))) float f32x4;
typedef __attribute__((ext_vector_type(16))) float f32x16;
typedef __attribute__((ext_vector_type(8))) _Float16 f16x8;
typedef __attribute__((ext_vector_type(4))) _Float16 f16x4;

__device__ __forceinline__ void gload_lds16(const void* g, void* l) {
  __builtin_amdgcn_global_load_lds((__attribute__((address_space(1))) void*)(g),
                                   (__attribute__((address_space(3))) void*)(l), 16, 0, 0);
}

// ---------------- cast fp32 -> fp16 ----------------
__global__ __launch_bounds__(256) void cast_f32_f16(const float* __restrict__ x,
                                                    _Float16* __restrict__ y, int n) {
  int i = (blockIdx.x * 256 + threadIdx.x) * 4;
  if (i < n) {
    float4 v = *(const float4*)(x + i);
    f16x4 o = { (_Float16)v.x, (_Float16)v.y, (_Float16)v.z, (_Float16)v.w };
    *(f16x4*)(y + i) = o;
  }
}

// ---- transpose+cast weights: W[2048][2048] f32 (k-major) -> Wt[n][k] f16 ----
__global__ __launch_bounds__(256) void wtrans(const float* __restrict__ W0, const float* __restrict__ W1,
                                              const float* __restrict__ W2, const float* __restrict__ W3,
                                              _Float16* __restrict__ out) {
  const float* W = blockIdx.z == 0 ? W0 : blockIdx.z == 1 ? W1 : blockIdx.z == 2 ? W2 : W3;
  _Float16* Wt = out + (size_t)blockIdx.z * (2048u * 2048u);
  __shared__ _Float16 tile[64][65];
  const int tid = threadIdx.x;
  const int k0 = blockIdx.y * 64, n0 = blockIdx.x * 64;
  #pragma unroll
  for (int p = 0; p < 4; ++p) {
    int o = p * 256 + tid, r = o >> 4, c = o & 15;
    float4 v = *(const float4*)(W + (size_t)(k0 + r) * 2048 + n0 + c * 4);
    tile[r][c * 4 + 0] = (_Float16)v.x;
    tile[r][c * 4 + 1] = (_Float16)v.y;
    tile[r][c * 4 + 2] = (_Float16)v.z;
    tile[r][c * 4 + 3] = (_Float16)v.w;
  }
  __syncthreads();
  #pragma unroll
  for (int p = 0; p < 2; ++p) {
    int o = p * 256 + tid, nl = o >> 3, c = o & 7;
    f16x8 u;
    #pragma unroll
    for (int i = 0; i < 8; ++i) u[i] = tile[c * 8 + i][nl];
    *(f16x8*)(Wt + (size_t)(n0 + nl) * 2048 + k0 + c * 8) = u;
  }
}

// ---- GEMM v3: C[M][N] = A[M][K] * Bt[N][K]^T, f16 in, OutT out.
// 128x128 tile, BK=64 (32KB LDS, half the barriers), mfma_32x32x16 (half the
// MFMA instructions per FLOP), XOR chunk swizzle (slot = chunk ^ (row&7)),
// swapped operands -> transposed C fragment -> row-contiguous vec4 stores.
template <typename OutT>
__global__ __launch_bounds__(256) void gemm_bt(const _Float16* __restrict__ A,
                                               const _Float16* __restrict__ Bt,
                                               OutT* __restrict__ C,
                                               int K, int N, size_t zsB, size_t zsC) {
  Bt += (size_t)blockIdx.z * zsB;
  C  += (size_t)blockIdx.z * zsC;
  __shared__ _Float16 As[128 * 64];
  __shared__ _Float16 Bs[128 * 64];
  const int tid = threadIdx.x;
  const int m0 = blockIdx.y * 128, n0 = blockIdx.x * 128;
  const int lane = tid & 63, w = tid >> 6, l32 = lane & 31, half = lane >> 5;
  const int wm = (w & 1) * 64, wn = (w >> 1) * 64;
  f32x16 acc[2][2];
  #pragma unroll
  for (int i = 0; i < 2; ++i)
    #pragma unroll
    for (int j = 0; j < 2; ++j) acc[i][j] = 0;

  for (int k0 = 0; k0 < K; k0 += 64) {
    __syncthreads();
    #pragma unroll
    for (int p = 0; p < 4; ++p) {
      int o = p * 256 + tid, r = o >> 3, c = o & 7;
      int cs = ((c ^ (r & 7)) * 8);  // LDS slot c holds global chunk c^(r&7)
      gload_lds16(A  + (size_t)(m0 + r) * K + k0 + cs, (char*)As + o * 16);
      gload_lds16(Bt + (size_t)(n0 + r) * K + k0 + cs, (char*)Bs + o * 16);
    }
    __builtin_amdgcn_s_waitcnt(0);
    __syncthreads();
    #pragma unroll
    for (int kk = 0; kk < 4; ++kk) {
      // A-frag (32x32x16): lane holds row=l32, k=(half)*8.. ; global chunk 2kk+half
      const int slot = ((2 * kk + half) ^ (l32 & 7)) * 8;
      f16x8 af[2], bf[2];
      #pragma unroll
      for (int s = 0; s < 2; ++s) {
        af[s] = *(const f16x8*)(As + (wm + s * 32 + l32) * 64 + slot);
        bf[s] = *(const f16x8*)(Bs + (wn + s * 32 + l32) * 64 + slot);
      }
      #pragma unroll
      for (int sm = 0; sm < 2; ++sm)
        #pragma unroll
        for (int sn = 0; sn < 2; ++sn)
          acc[sm][sn] = __builtin_amdgcn_mfma_f32_32x32x16_f16(bf[sn], af[sm], acc[sm][sn], 0, 0, 0);
    }
  }
  // transposed C frag: lane -> row m = l32(+tile); cols n = (re&3)+8*(re>>2)+4*half
  #pragma unroll
  for (int sm = 0; sm < 2; ++sm) {
    const size_t row = (size_t)(m0 + wm + sm * 32 + l32);
    #pragma unroll
    for (int sn = 0; sn < 2; ++sn) {
      #pragma unroll
      for (int g = 0; g < 4; ++g) {
        const int col = n0 + wn + sn * 32 + g * 8 + 4 * half;
        if constexpr (sizeof(OutT) == 2) {
          f16x4 o = { (_Float16)acc[sm][sn][4 * g + 0], (_Float16)acc[sm][sn][4 * g + 1],
                      (_Float16)acc[sm][sn][4 * g + 2], (_Float16)acc[sm][sn][4 * g + 3] };
          *(f16x4*)((_Float16*)C + row * N + col) = o;
        } else {
          f32x4 o = { acc[sm][sn][4 * g + 0], acc[sm][sn][4 * g + 1],
                      acc[sm][sn][4 * g + 2], acc[sm][sn][4 * g + 3] };
          *(f32x4*)((float*)C + row * N + col) = o;
        }
      }
    }
  }
}

// ---- block-sparse attention: WG = (q-tile of 128, head, batch).
// Waves 0-1 own q-block 2t, waves 2-3 own 2t+1 -> per-wave uniform block validity.
// Online softmax; S^T = K.Q^T; O^T += V^T.P^T with P^T straight from C-layout regs.
// V^T comes directly from the swapped GEMM: Vt[h*128+d][b*2048+s].
__global__ __launch_bounds__(256) void attn(const _Float16* __restrict__ Qg,
                                            const _Float16* __restrict__ Kg,
                                            const _Float16* __restrict__ Vtg,
                                            _Float16* __restrict__ Og) {
  const int t = blockIdx.x, h = blockIdx.y, b = blockIdx.z;
  __shared__ _Float16 Qs[128 * 128];  // 32 KB
  __shared__ _Float16 Ks[64 * 128];   // 16 KB
  __shared__ _Float16 Vs[128 * 64];   // 16 KB
  const int tid = threadIdx.x;
  const int lane = tid & 63, w = tid >> 6, l16 = lane & 15, quad = lane >> 4;
  const int qbw = 2 * t + (w >> 1);   // this wave's q-block
  const char* QsB = (const char*)Qs;
  const char* KsB = (const char*)Ks;
  const char* VsB = (const char*)Vs;

  #pragma unroll
  for (int p = 0; p < 8; ++p) {
    int o = p * 256 + tid, r = o >> 4, c = o & 15;
    gload_lds16(Qg + (size_t)(b * 2048 + t * 128 + r) * 2048 + h * 128 + ((c ^ (r & 15)) * 8),
                (char*)Qs + o * 16);
  }
  __builtin_amdgcn_s_waitcnt(0);
  __syncthreads();
  f16x8 qf[2][4];
  #pragma unroll
  for (int qc = 0; qc < 2; ++qc)
    #pragma unroll
    for (int ks = 0; ks < 4; ++ks)
      qf[qc][ks] = *(const f16x8*)(QsB + (w * 32 + qc * 16 + l16) * 256 +
                                   (((ks * 4 + quad) ^ l16) * 16));

  const float scale = 0.08838834764831845f;  // 1/sqrt(128)
  float m_[2] = {-1e30f, -1e30f}, l_[2] = {0.f, 0.f};
  f32x4 oacc[8][2];
  #pragma unroll
  for (int dt = 0; dt < 8; ++dt)
    #pragma unroll
    for (int qc = 0; qc < 2; ++qc) oacc[dt][qc] = (f32x4){0.f, 0.f, 0.f, 0.f};

  for (int jj = 0; jj < 6; ++jj) {
    const int j = 2 * t - 2 + jj;
    const int jc = j < 0 ? 0 : (j > 31 ? 31 : j);
    __syncthreads();
    #pragma unroll
    for (int p = 0; p < 4; ++p) {
      int o = p * 256 + tid, r = o >> 4, c = o & 15;
      gload_lds16(Kg + (size_t)(b * 2048 + jc * 64 + r) * 2048 + h * 128 + ((c ^ (r & 15)) * 8),
                  (char*)Ks + o * 16);
    }
    #pragma unroll
    for (int p = 0; p < 4; ++p) {
      int o = p * 256 + tid, d = o >> 3, c = o & 7;
      gload_lds16(Vtg + (size_t)(h * 128 + d) * 4096 + b * 2048 + jc * 64 + ((c ^ (d & 7)) * 8),
                  (char*)Vs + o * 16);
    }
    __builtin_amdgcn_s_waitcnt(0);
    __syncthreads();

    const bool valid = (j >= 0) && (j <= 31) && (j >= qbw - 2) && (j <= qbw + 2);
    if (valid) {
      f32x4 sc[4][2];
      #pragma unroll
      for (int kt = 0; kt < 4; ++kt)
        #pragma unroll
        for (int qc = 0; qc < 2; ++qc) sc[kt][qc] = (f32x4){0.f, 0.f, 0.f, 0.f};
      #pragma unroll
      for (int kt = 0; kt < 4; ++kt)
        #pragma unroll
        for (int ks = 0; ks < 4; ++ks) {
          f16x8 kf = *(const f16x8*)(KsB + (kt * 16 + l16) * 256 + (((ks * 4 + quad) ^ l16) * 16));
          #pragma unroll
          for (int qc = 0; qc < 2; ++qc)
            sc[kt][qc] = __builtin_amdgcn_mfma_f32_16x16x32_f16(kf, qf[qc][ks], sc[kt][qc], 0, 0, 0);
        }
      #pragma unroll
      for (int qc = 0; qc < 2; ++qc) {
        float mj = -1e30f;
        #pragma unroll
        for (int kt = 0; kt < 4; ++kt)
          #pragma unroll
          for (int r = 0; r < 4; ++r) {
            float v = sc[kt][qc][r] * scale;
            sc[kt][qc][r] = v;
            mj = fmaxf(mj, v);
          }
        mj = fmaxf(mj, __shfl_xor(mj, 16));
        mj = fmaxf(mj, __shfl_xor(mj, 32));
        const float mn = fmaxf(m_[qc], mj);
        const float alpha = __expf(m_[qc] - mn);
        float s_ = 0.f;
        #pragma unroll
        for (int kt = 0; kt < 4; ++kt)
          #pragma unroll
          for (int r = 0; r < 4; ++r) {
            float p = __expf(sc[kt][qc][r] - mn);
            sc[kt][qc][r] = p;
            s_ += p;
          }
        s_ += __shfl_xor(s_, 16);
        s_ += __shfl_xor(s_, 32);
        l_[qc] = l_[qc] * alpha + s_;
        m_[qc] = mn;
        #pragma unroll
        for (int dt = 0; dt < 8; ++dt) oacc[dt][qc] *= alpha;
      }
      #pragma unroll
      for (int kt = 0; kt < 4; ++kt) {
        f16x4 pb[2];
        #pragma unroll
        for (int qc = 0; qc < 2; ++qc)
          pb[qc] = (f16x4){ (_Float16)sc[kt][qc][0], (_Float16)sc[kt][qc][1],
                            (_Float16)sc[kt][qc][2], (_Float16)sc[kt][qc][3] };
        #pragma unroll
        for (int dt = 0; dt < 8; ++dt) {
          f16x4 vv = *(const f16x4*)(VsB + (dt * 16 + l16) * 128 +
                                     (((2 * kt + (quad >> 1)) ^ (l16 & 7)) * 16) + (quad & 1) * 8);
          #pragma unroll
          for (int qc = 0; qc < 2; ++qc)
            oacc[dt][qc] = __builtin_amdgcn_mfma_f32_16x16x16f16(vv, pb[qc], oacc[dt][qc], 0, 0, 0);
        }
      }
    }
  }

  #pragma unroll
  for (int qc = 0; qc < 2; ++qc) {
    const float pinv = 1.0f / l_[qc];
    const size_t orow = (size_t)(b * 2048 + t * 128 + w * 32 + qc * 16 + l16);
    #pragma unroll
    for (int dt = 0; dt < 8; ++dt) {
      f16x4 ov = { (_Float16)(oacc[dt][qc][0] * pinv), (_Float16)(oacc[dt][qc][1] * pinv),
                   (_Float16)(oacc[dt][qc][2] * pinv), (_Float16)(oacc[dt][qc][3] * pinv) };
      *(f16x4*)(Og + orow * 2048 + h * 128 + dt * 16 + quad * 4) = ov;
    }
  }
}

extern "C" void kernel_launch(void* const* d_in, const int* in_sizes, int n_in,
                              void* d_out, int out_size, void* d_ws, size_t ws_size,
                              hipStream_t stream) {
  const float* Hs = (const float*)d_in[0];
  const float* Wq = (const float*)d_in[1];
  const float* Wk = (const float*)d_in[2];
  const float* Wv = (const float*)d_in[3];
  const float* Wo = (const float*)d_in[4];
  _Float16* Hb  = (_Float16*)d_ws;          // H cast  [4096][2048]
  _Float16* Wt  = Hb  + 8388608;            // Wq/Wk/Wv/Wo^T  4 x [2048][2048]
  _Float16* Qb  = Wt  + 16777216;           // Q  [b*2048+s][h*128+d]
  _Float16* Kb  = Qb  + 8388608;            // K  [b*2048+s][h*128+d]
  _Float16* Vtb = Kb  + 8388608;            // V^T [h*128+d][b*2048+s]  (direct from GEMM)
  _Float16* Ob  = Vtb + 8388608;            // attn out [b*2048+s][h*128+d]
  float* out = (float*)d_out;

  cast_f32_f16<<<8192, 256, 0, stream>>>(Hs, Hb, 8388608);
  wtrans<<<dim3(32, 32, 4), 256, 0, stream>>>(Wq, Wk, Wv, Wo, Wt);
  // Q, K: C[b*2048+s][h*128+d] = Hb . W^T
  gemm_bt<_Float16><<<dim3(16, 32, 2), 256, 0, stream>>>(Hb, Wt, Qb, 2048, 2048,
                                                         (size_t)4194304, (size_t)8388608);
  // V^T: C[h*128+d][b*2048+s] = WvT . Hb^T
  gemm_bt<_Float16><<<dim3(32, 16, 1), 256, 0, stream>>>(Wt + 2 * 4194304, Hb, Vtb, 2048, 4096,
                                                         (size_t)0, (size_t)0);
  attn<<<dim3(16, 16, 2), 256, 0, stream>>>(Qb, Kb, Vtb, Ob);
  gemm_bt<float><<<dim3(16, 32, 1), 256, 0, stream>>>(Ob, Wt + 3 * 4194304, out, 2048, 2048,
                                                      (size_t)0, (size_t)0);
}

// Round 5
// 356.295 us; speedup vs baseline: 1.0897x; 1.0212x over previous
//
#include <hip/hip_runtime.h>

typedef __attribute__((ext_vector_type(4))) float f32x4;
typedef __attribute__((ext_vector_type(16))) float f32x16;
typedef __attribute__((ext_vector_type(8))) _Float16 f16x8;
typedef __attribute__((ext_vector_type(4))) _Float16 f16x4;

__device__ __forceinline__ void gload_lds16(const void* g, void* l) {
  __builtin_amdgcn_global_load_lds((__attribute__((address_space(1))) void*)(g),
                                   (__attribute__((address_space(3))) void*)(l), 16, 0, 0);
}

// ---------------- cast fp32 -> fp16 ----------------
__global__ __launch_bounds__(256) void cast_f32_f16(const float* __restrict__ x,
                                                    _Float16* __restrict__ y, int n) {
  int i = (blockIdx.x * 256 + threadIdx.x) * 4;
  if (i < n) {
    float4 v = *(const float4*)(x + i);
    f16x4 o = { (_Float16)v.x, (_Float16)v.y, (_Float16)v.z, (_Float16)v.w };
    *(f16x4*)(y + i) = o;
  }
}

// ---- transpose+cast weights: W[2048][2048] f32 (k-major) -> Wt[n][k] f16 ----
__global__ __launch_bounds__(256) void wtrans(const float* __restrict__ W0, const float* __restrict__ W1,
                                              const float* __restrict__ W2, const float* __restrict__ W3,
                                              _Float16* __restrict__ out) {
  const float* W = blockIdx.z == 0 ? W0 : blockIdx.z == 1 ? W1 : blockIdx.z == 2 ? W2 : W3;
  _Float16* Wt = out + (size_t)blockIdx.z * (2048u * 2048u);
  __shared__ _Float16 tile[64][65];
  const int tid = threadIdx.x;
  const int k0 = blockIdx.y * 64, n0 = blockIdx.x * 64;
  #pragma unroll
  for (int p = 0; p < 4; ++p) {
    int o = p * 256 + tid, r = o >> 4, c = o & 15;
    float4 v = *(const float4*)(W + (size_t)(k0 + r) * 2048 + n0 + c * 4);
    tile[r][c * 4 + 0] = (_Float16)v.x;
    tile[r][c * 4 + 1] = (_Float16)v.y;
    tile[r][c * 4 + 2] = (_Float16)v.z;
    tile[r][c * 4 + 3] = (_Float16)v.w;
  }
  __syncthreads();
  #pragma unroll
  for (int p = 0; p < 2; ++p) {
    int o = p * 256 + tid, nl = o >> 3, c = o & 7;
    f16x8 u;
    #pragma unroll
    for (int i = 0; i < 8; ++i) u[i] = tile[c * 8 + i][nl];
    *(f16x8*)(Wt + (size_t)(n0 + nl) * 2048 + k0 + c * 8) = u;
  }
}

// ---- GEMM big-tile: 256x128 WG tile, BK=64, wave tile 128x64 (acc 4x2 f32x16).
// 6 LDS fragment reads per 8 MFMA (24 B/KFLOP) and 8 independent acc chains.
template <typename OutT>
__global__ __launch_bounds__(256, 2) void gemm_big(const _Float16* __restrict__ A,
                                                   const _Float16* __restrict__ Bt,
                                                   OutT* __restrict__ C,
                                                   int K, int N, size_t zsB, size_t zsC) {
  Bt += (size_t)blockIdx.z * zsB;
  C  += (size_t)blockIdx.z * zsC;
  __shared__ _Float16 As[256 * 64];   // 32 KB
  __shared__ _Float16 Bs[128 * 64];   // 16 KB
  const int tid = threadIdx.x;
  const int m0 = blockIdx.y * 256, n0 = blockIdx.x * 128;
  const int lane = tid & 63, w = tid >> 6, l32 = lane & 31, half = lane >> 5;
  const int wm = (w & 1) * 128, wn = (w >> 1) * 64;
  f32x16 acc[4][2];
  #pragma unroll
  for (int s = 0; s < 4; ++s)
    #pragma unroll
    for (int t = 0; t < 2; ++t) acc[s][t] = 0;

  for (int k0 = 0; k0 < K; k0 += 64) {
    __syncthreads();
    #pragma unroll
    for (int p = 0; p < 8; ++p) {
      int o = p * 256 + tid, r = o >> 3, c = o & 7;
      int cs = ((c ^ (r & 7)) * 8);
      gload_lds16(A + (size_t)(m0 + r) * K + k0 + cs, (char*)As + o * 16);
    }
    #pragma unroll
    for (int p = 0; p < 4; ++p) {
      int o = p * 256 + tid, r = o >> 3, c = o & 7;
      int cs = ((c ^ (r & 7)) * 8);
      gload_lds16(Bt + (size_t)(n0 + r) * K + k0 + cs, (char*)Bs + o * 16);
    }
    __builtin_amdgcn_s_waitcnt(0);
    __syncthreads();
    #pragma unroll
    for (int kk = 0; kk < 4; ++kk) {
      const int slot = ((2 * kk + half) ^ (l32 & 7)) * 8;
      f16x8 af[4], bf[2];
      #pragma unroll
      for (int s = 0; s < 4; ++s) af[s] = *(const f16x8*)(As + (wm + s * 32 + l32) * 64 + slot);
      #pragma unroll
      for (int t = 0; t < 2; ++t) bf[t] = *(const f16x8*)(Bs + (wn + t * 32 + l32) * 64 + slot);
      #pragma unroll
      for (int s = 0; s < 4; ++s)
        #pragma unroll
        for (int t = 0; t < 2; ++t)
          acc[s][t] = __builtin_amdgcn_mfma_f32_32x32x16_f16(bf[t], af[s], acc[s][t], 0, 0, 0);
    }
  }
  #pragma unroll
  for (int s = 0; s < 4; ++s) {
    const size_t row = (size_t)(m0 + wm + s * 32 + l32);
    #pragma unroll
    for (int t = 0; t < 2; ++t) {
      #pragma unroll
      for (int g = 0; g < 4; ++g) {
        const int col = n0 + wn + t * 32 + g * 8 + 4 * half;
        if constexpr (sizeof(OutT) == 2) {
          f16x4 o = { (_Float16)acc[s][t][4 * g + 0], (_Float16)acc[s][t][4 * g + 1],
                      (_Float16)acc[s][t][4 * g + 2], (_Float16)acc[s][t][4 * g + 3] };
          *(f16x4*)((_Float16*)C + row * N + col) = o;
        } else {
          f32x4 o = { acc[s][t][4 * g + 0], acc[s][t][4 * g + 1],
                      acc[s][t][4 * g + 2], acc[s][t][4 * g + 3] };
          *(f32x4*)((float*)C + row * N + col) = o;
        }
      }
    }
  }
}

// ---- GEMM v3 (round-4): 128x128 tile, BK=64, wave 64x64 — for 256-WG shapes ----
template <typename OutT>
__global__ __launch_bounds__(256) void gemm_bt(const _Float16* __restrict__ A,
                                               const _Float16* __restrict__ Bt,
                                               OutT* __restrict__ C,
                                               int K, int N, size_t zsB, size_t zsC) {
  Bt += (size_t)blockIdx.z * zsB;
  C  += (size_t)blockIdx.z * zsC;
  __shared__ _Float16 As[128 * 64];
  __shared__ _Float16 Bs[128 * 64];
  const int tid = threadIdx.x;
  const int m0 = blockIdx.y * 128, n0 = blockIdx.x * 128;
  const int lane = tid & 63, w = tid >> 6, l32 = lane & 31, half = lane >> 5;
  const int wm = (w & 1) * 64, wn = (w >> 1) * 64;
  f32x16 acc[2][2];
  #pragma unroll
  for (int i = 0; i < 2; ++i)
    #pragma unroll
    for (int j = 0; j < 2; ++j) acc[i][j] = 0;

  for (int k0 = 0; k0 < K; k0 += 64) {
    __syncthreads();
    #pragma unroll
    for (int p = 0; p < 4; ++p) {
      int o = p * 256 + tid, r = o >> 3, c = o & 7;
      int cs = ((c ^ (r & 7)) * 8);
      gload_lds16(A  + (size_t)(m0 + r) * K + k0 + cs, (char*)As + o * 16);
      gload_lds16(Bt + (size_t)(n0 + r) * K + k0 + cs, (char*)Bs + o * 16);
    }
    __builtin_amdgcn_s_waitcnt(0);
    __syncthreads();
    #pragma unroll
    for (int kk = 0; kk < 4; ++kk) {
      const int slot = ((2 * kk + half) ^ (l32 & 7)) * 8;
      f16x8 af[2], bf[2];
      #pragma unroll
      for (int s = 0; s < 2; ++s) {
        af[s] = *(const f16x8*)(As + (wm + s * 32 + l32) * 64 + slot);
        bf[s] = *(const f16x8*)(Bs + (wn + s * 32 + l32) * 64 + slot);
      }
      #pragma unroll
      for (int sm = 0; sm < 2; ++sm)
        #pragma unroll
        for (int sn = 0; sn < 2; ++sn)
          acc[sm][sn] = __builtin_amdgcn_mfma_f32_32x32x16_f16(bf[sn], af[sm], acc[sm][sn], 0, 0, 0);
    }
  }
  #pragma unroll
  for (int sm = 0; sm < 2; ++sm) {
    const size_t row = (size_t)(m0 + wm + sm * 32 + l32);
    #pragma unroll
    for (int sn = 0; sn < 2; ++sn) {
      #pragma unroll
      for (int g = 0; g < 4; ++g) {
        const int col = n0 + wn + sn * 32 + g * 8 + 4 * half;
        if constexpr (sizeof(OutT) == 2) {
          f16x4 o = { (_Float16)acc[sm][sn][4 * g + 0], (_Float16)acc[sm][sn][4 * g + 1],
                      (_Float16)acc[sm][sn][4 * g + 2], (_Float16)acc[sm][sn][4 * g + 3] };
          *(f16x4*)((_Float16*)C + row * N + col) = o;
        } else {
          f32x4 o = { acc[sm][sn][4 * g + 0], acc[sm][sn][4 * g + 1],
                      acc[sm][sn][4 * g + 2], acc[sm][sn][4 * g + 3] };
          *(f32x4*)((float*)C + row * N + col) = o;
        }
      }
    }
  }
}

// ---- block-sparse attention (round-3 structure, V^T direct from GEMM) ----
__global__ __launch_bounds__(256) void attn(const _Float16* __restrict__ Qg,
                                            const _Float16* __restrict__ Kg,
                                            const _Float16* __restrict__ Vtg,
                                            _Float16* __restrict__ Og) {
  const int t = blockIdx.x, h = blockIdx.y, b = blockIdx.z;
  __shared__ _Float16 Qs[128 * 128];  // 32 KB
  __shared__ _Float16 Ks[64 * 128];   // 16 KB
  __shared__ _Float16 Vs[128 * 64];   // 16 KB
  const int tid = threadIdx.x;
  const int lane = tid & 63, w = tid >> 6, l16 = lane & 15, quad = lane >> 4;
  const int qbw = 2 * t + (w >> 1);
  const char* QsB = (const char*)Qs;
  const char* KsB = (const char*)Ks;
  const char* VsB = (const char*)Vs;

  #pragma unroll
  for (int p = 0; p < 8; ++p) {
    int o = p * 256 + tid, r = o >> 4, c = o & 15;
    gload_lds16(Qg + (size_t)(b * 2048 + t * 128 + r) * 2048 + h * 128 + ((c ^ (r & 15)) * 8),
                (char*)Qs + o * 16);
  }
  __builtin_amdgcn_s_waitcnt(0);
  __syncthreads();
  f16x8 qf[2][4];
  #pragma unroll
  for (int qc = 0; qc < 2; ++qc)
    #pragma unroll
    for (int ks = 0; ks < 4; ++ks)
      qf[qc][ks] = *(const f16x8*)(QsB + (w * 32 + qc * 16 + l16) * 256 +
                                   (((ks * 4 + quad) ^ l16) * 16));

  const float scale = 0.08838834764831845f;  // 1/sqrt(128)
  float m_[2] = {-1e30f, -1e30f}, l_[2] = {0.f, 0.f};
  f32x4 oacc[8][2];
  #pragma unroll
  for (int dt = 0; dt < 8; ++dt)
    #pragma unroll
    for (int qc = 0; qc < 2; ++qc) oacc[dt][qc] = (f32x4){0.f, 0.f, 0.f, 0.f};

  for (int jj = 0; jj < 6; ++jj) {
    const int j = 2 * t - 2 + jj;
    const int jc = j < 0 ? 0 : (j > 31 ? 31 : j);
    __syncthreads();
    #pragma unroll
    for (int p = 0; p < 4; ++p) {
      int o = p * 256 + tid, r = o >> 4, c = o & 15;
      gload_lds16(Kg + (size_t)(b * 2048 + jc * 64 + r) * 2048 + h * 128 + ((c ^ (r & 15)) * 8),
                  (char*)Ks + o * 16);
    }
    #pragma unroll
    for (int p = 0; p < 4; ++p) {
      int o = p * 256 + tid, d = o >> 3, c = o & 7;
      gload_lds16(Vtg + (size_t)(h * 128 + d) * 4096 + b * 2048 + jc * 64 + ((c ^ (d & 7)) * 8),
                  (char*)Vs + o * 16);
    }
    __builtin_amdgcn_s_waitcnt(0);
    __syncthreads();

    const bool valid = (j >= 0) && (j <= 31) && (j >= qbw - 2) && (j <= qbw + 2);
    if (valid) {
      f32x4 sc[4][2];
      #pragma unroll
      for (int kt = 0; kt < 4; ++kt)
        #pragma unroll
        for (int qc = 0; qc < 2; ++qc) sc[kt][qc] = (f32x4){0.f, 0.f, 0.f, 0.f};
      #pragma unroll
      for (int kt = 0; kt < 4; ++kt)
        #pragma unroll
        for (int ks = 0; ks < 4; ++ks) {
          f16x8 kf = *(const f16x8*)(KsB + (kt * 16 + l16) * 256 + (((ks * 4 + quad) ^ l16) * 16));
          #pragma unroll
          for (int qc = 0; qc < 2; ++qc)
            sc[kt][qc] = __builtin_amdgcn_mfma_f32_16x16x32_f16(kf, qf[qc][ks], sc[kt][qc], 0, 0, 0);
        }
      #pragma unroll
      for (int qc = 0; qc < 2; ++qc) {
        float mj = -1e30f;
        #pragma unroll
        for (int kt = 0; kt < 4; ++kt)
          #pragma unroll
          for (int r = 0; r < 4; ++r) {
            float v = sc[kt][qc][r] * scale;
            sc[kt][qc][r] = v;
            mj = fmaxf(mj, v);
          }
        mj = fmaxf(mj, __shfl_xor(mj, 16));
        mj = fmaxf(mj, __shfl_xor(mj, 32));
        const float mn = fmaxf(m_[qc], mj);
        const float alpha = __expf(m_[qc] - mn);
        float s_ = 0.f;
        #pragma unroll
        for (int kt = 0; kt < 4; ++kt)
          #pragma unroll
          for (int r = 0; r < 4; ++r) {
            float p = __expf(sc[kt][qc][r] - mn);
            sc[kt][qc][r] = p;
            s_ += p;
          }
        s_ += __shfl_xor(s_, 16);
        s_ += __shfl_xor(s_, 32);
        l_[qc] = l_[qc] * alpha + s_;
        m_[qc] = mn;
        #pragma unroll
        for (int dt = 0; dt < 8; ++dt) oacc[dt][qc] *= alpha;
      }
      #pragma unroll
      for (int kt = 0; kt < 4; ++kt) {
        f16x4 pb[2];
        #pragma unroll
        for (int qc = 0; qc < 2; ++qc)
          pb[qc] = (f16x4){ (_Float16)sc[kt][qc][0], (_Float16)sc[kt][qc][1],
                            (_Float16)sc[kt][qc][2], (_Float16)sc[kt][qc][3] };
        #pragma unroll
        for (int dt = 0; dt < 8; ++dt) {
          f16x4 vv = *(const f16x4*)(VsB + (dt * 16 + l16) * 128 +
                                     (((2 * kt + (quad >> 1)) ^ (l16 & 7)) * 16) + (quad & 1) * 8);
          #pragma unroll
          for (int qc = 0; qc < 2; ++qc)
            oacc[dt][qc] = __builtin_amdgcn_mfma_f32_16x16x16f16(vv, pb[qc], oacc[dt][qc], 0, 0, 0);
        }
      }
    }
  }

  #pragma unroll
  for (int qc = 0; qc < 2; ++qc) {
    const float pinv = 1.0f / l_[qc];
    const size_t orow = (size_t)(b * 2048 + t * 128 + w * 32 + qc * 16 + l16);
    #pragma unroll
    for (int dt = 0; dt < 8; ++dt) {
      f16x4 ov = { (_Float16)(oacc[dt][qc][0] * pinv), (_Float16)(oacc[dt][qc][1] * pinv),
                   (_Float16)(oacc[dt][qc][2] * pinv), (_Float16)(oacc[dt][qc][3] * pinv) };
      *(f16x4*)(Og + orow * 2048 + h * 128 + dt * 16 + quad * 4) = ov;
    }
  }
}

extern "C" void kernel_launch(void* const* d_in, const int* in_sizes, int n_in,
                              void* d_out, int out_size, void* d_ws, size_t ws_size,
                              hipStream_t stream) {
  const float* Hs = (const float*)d_in[0];
  const float* Wq = (const float*)d_in[1];
  const float* Wk = (const float*)d_in[2];
  const float* Wv = (const float*)d_in[3];
  const float* Wo = (const float*)d_in[4];
  _Float16* Hb  = (_Float16*)d_ws;          // H cast  [4096][2048]
  _Float16* Wt  = Hb  + 8388608;            // Wq/Wk/Wv/Wo^T  4 x [2048][2048]
  _Float16* Qb  = Wt  + 16777216;           // Q  [b*2048+s][h*128+d]
  _Float16* Kb  = Qb  + 8388608;            // K  [b*2048+s][h*128+d]
  _Float16* Vtb = Kb  + 8388608;            // V^T [h*128+d][b*2048+s]
  _Float16* Ob  = Vtb + 8388608;            // attn out [b*2048+s][h*128+d]
  float* out = (float*)d_out;

  cast_f32_f16<<<8192, 256, 0, stream>>>(Hs, Hb, 8388608);
  wtrans<<<dim3(32, 32, 4), 256, 0, stream>>>(Wq, Wk, Wv, Wo, Wt);
  // Q, K: big-tile (256x128), grid 16x16x2 = 512 WGs
  gemm_big<_Float16><<<dim3(16, 16, 2), 256, 0, stream>>>(Hb, Wt, Qb, 2048, 2048,
                                                          (size_t)4194304, (size_t)8388608);
  // V^T: C[h*128+d][b*2048+s] = WvT . Hb^T  (128-tile kernel, 512 WGs)
  gemm_bt<_Float16><<<dim3(32, 16, 1), 256, 0, stream>>>(Wt + 2 * 4194304, Hb, Vtb, 2048, 4096,
                                                         (size_t)0, (size_t)0);
  attn<<<dim3(16, 16, 2), 256, 0, stream>>>(Qb, Kb, Vtb, Ob);
  gemm_bt<float><<<dim3(16, 32, 1), 256, 0, stream>>>(Ob, Wt + 3 * 4194304, out, 2048, 2048,
                                                      (size_t)0, (size_t)0);
}

// Round 6
// 349.259 us; speedup vs baseline: 1.1116x; 1.0201x over previous
//
#include <hip/hip_runtime.h>

typedef __attribute__((ext_vector_type(4))) float f32x4;
typedef __attribute__((ext_vector_type(16))) float f32x16;
typedef __attribute__((ext_vector_type(8))) _Float16 f16x8;
typedef __attribute__((ext_vector_type(4))) _Float16 f16x4;

__device__ __forceinline__ void gload_lds16(const void* g, void* l) {
  __builtin_amdgcn_global_load_lds((__attribute__((address_space(1))) void*)(g),
                                   (__attribute__((address_space(3))) void*)(l), 16, 0, 0);
}

// ---- fused prep: cast H fp32->fp16 (blocks 0..8191) + weight transpose-cast
// (blocks 8192..12287, mapping the old (32,32,4) wtrans grid) ----
__global__ __launch_bounds__(256) void prep(const float* __restrict__ Hs,
                                            const float* __restrict__ W0, const float* __restrict__ W1,
                                            const float* __restrict__ W2, const float* __restrict__ W3,
                                            _Float16* __restrict__ Hb, _Float16* __restrict__ Wt) {
  __shared__ _Float16 tile[64][65];
  const int bid = blockIdx.x, tid = threadIdx.x;
  if (bid < 8192) {
    int i = (bid * 256 + tid) * 4;
    float4 v = *(const float4*)(Hs + i);
    f16x4 o = { (_Float16)v.x, (_Float16)v.y, (_Float16)v.z, (_Float16)v.w };
    *(f16x4*)(Hb + i) = o;
    return;
  }
  const int t = bid - 8192;
  const int z = t >> 10, k0 = ((t >> 5) & 31) * 64, n0 = (t & 31) * 64;
  const float* W = z == 0 ? W0 : z == 1 ? W1 : z == 2 ? W2 : W3;
  _Float16* Wo_ = Wt + (size_t)z * (2048u * 2048u);
  #pragma unroll
  for (int p = 0; p < 4; ++p) {
    int o = p * 256 + tid, r = o >> 4, c = o & 15;
    float4 v = *(const float4*)(W + (size_t)(k0 + r) * 2048 + n0 + c * 4);
    tile[r][c * 4 + 0] = (_Float16)v.x;
    tile[r][c * 4 + 1] = (_Float16)v.y;
    tile[r][c * 4 + 2] = (_Float16)v.z;
    tile[r][c * 4 + 3] = (_Float16)v.w;
  }
  __syncthreads();
  #pragma unroll
  for (int p = 0; p < 2; ++p) {
    int o = p * 256 + tid, nl = o >> 3, c = o & 7;
    f16x8 u;
    #pragma unroll
    for (int i = 0; i < 8; ++i) u[i] = tile[c * 8 + i][nl];
    *(f16x8*)(Wo_ + (size_t)(n0 + nl) * 2048 + k0 + c * 8) = u;
  }
}

// ---- generic big-tile GEMM tile: WG tile (SM*64) x (SN*64), BK=64, 48KB LDS.
// Wave tile (SM*32) x (SN*32), acc SM x SN f32x16. XOR chunk swizzle.
// Swapped MFMA operands -> transposed C frag -> row-contiguous vec4 stores.
template <int SM, int SN, typename OutT>
__device__ __forceinline__ void gemm_tile(const _Float16* __restrict__ A,
                                          const _Float16* __restrict__ Bt,
                                          OutT* __restrict__ C,
                                          int K, int N, int m0, int n0, _Float16* S) {
  _Float16* As = S;                    // (SM*64) x 64
  _Float16* Bs = S + SM * 64 * 64;     // (SN*64) x 64
  const int tid = threadIdx.x;
  const int lane = tid & 63, w = tid >> 6, l32 = lane & 31, half = lane >> 5;
  const int wm = (w & 1) * SM * 32, wn = (w >> 1) * SN * 32;
  f32x16 acc[SM][SN];
  #pragma unroll
  for (int s = 0; s < SM; ++s)
    #pragma unroll
    for (int t = 0; t < SN; ++t) acc[s][t] = 0;

  for (int k0 = 0; k0 < K; k0 += 64) {
    __syncthreads();
    #pragma unroll
    for (int p = 0; p < SM * 2; ++p) {
      int o = p * 256 + tid, r = o >> 3, c = o & 7;
      gload_lds16(A + (size_t)(m0 + r) * K + k0 + ((c ^ (r & 7)) * 8), (char*)As + o * 16);
    }
    #pragma unroll
    for (int p = 0; p < SN * 2; ++p) {
      int o = p * 256 + tid, r = o >> 3, c = o & 7;
      gload_lds16(Bt + (size_t)(n0 + r) * K + k0 + ((c ^ (r & 7)) * 8), (char*)Bs + o * 16);
    }
    __builtin_amdgcn_s_waitcnt(0);
    __syncthreads();
    #pragma unroll
    for (int kk = 0; kk < 4; ++kk) {
      const int slot = ((2 * kk + half) ^ (l32 & 7)) * 8;
      f16x8 af[SM], bf[SN];
      #pragma unroll
      for (int s = 0; s < SM; ++s) af[s] = *(const f16x8*)(As + (wm + s * 32 + l32) * 64 + slot);
      #pragma unroll
      for (int t = 0; t < SN; ++t) bf[t] = *(const f16x8*)(Bs + (wn + t * 32 + l32) * 64 + slot);
      #pragma unroll
      for (int s = 0; s < SM; ++s)
        #pragma unroll
        for (int t = 0; t < SN; ++t)
          acc[s][t] = __builtin_amdgcn_mfma_f32_32x32x16_f16(bf[t], af[s], acc[s][t], 0, 0, 0);
    }
  }
  #pragma unroll
  for (int s = 0; s < SM; ++s) {
    const size_t row = (size_t)(m0 + wm + s * 32 + l32);
    #pragma unroll
    for (int t = 0; t < SN; ++t) {
      #pragma unroll
      for (int g = 0; g < 4; ++g) {
        const int col = n0 + wn + t * 32 + g * 8 + 4 * half;
        if constexpr (sizeof(OutT) == 2) {
          f16x4 o = { (_Float16)acc[s][t][4 * g + 0], (_Float16)acc[s][t][4 * g + 1],
                      (_Float16)acc[s][t][4 * g + 2], (_Float16)acc[s][t][4 * g + 3] };
          *(f16x4*)((_Float16*)C + row * N + col) = o;
        } else {
          f32x4 o = { acc[s][t][4 * g + 0], acc[s][t][4 * g + 1],
                      acc[s][t][4 * g + 2], acc[s][t][4 * g + 3] };
          *(f32x4*)((float*)C + row * N + col) = o;
        }
      }
    }
  }
}

// ---- fused QKV + V^T: 768 WGs -> 3 WGs/CU (48KB LDS each).
// Blocks 0..511: Q/K (z = id>>8), C[4096][2048] = Hb . Wt^T, 256x128 tiles.
// Blocks 512..767: V^T, C[2048][4096] = WvT . Hb^T, 128x256 tiles.
__global__ __launch_bounds__(256, 2) void qkvv(const _Float16* __restrict__ Hb,
                                               const _Float16* __restrict__ Wt,
                                               _Float16* __restrict__ Qb,
                                               _Float16* __restrict__ Vtb) {
  __shared__ _Float16 S[24576];  // 48 KB
  const int id = blockIdx.x;
  if (id < 512) {
    const int z = id >> 8, t = id & 255;
    gemm_tile<4, 2>(Hb, Wt + (size_t)z * 4194304, Qb + (size_t)z * 8388608,
                    2048, 2048, (t >> 4) * 256, (t & 15) * 128, S);
  } else {
    const int t = id - 512;
    gemm_tile<2, 4>(Wt + (size_t)2 * 4194304, Hb, Vtb,
                    2048, 4096, (t >> 4) * 128, (t & 15) * 256, S);
  }
}

// ---- Wo GEMM: 128x128 tile, BK=64 (512 WGs, 2/CU) ----
__global__ __launch_bounds__(256) void gemm_wo(const _Float16* __restrict__ A,
                                               const _Float16* __restrict__ Bt,
                                               float* __restrict__ C) {
  __shared__ _Float16 S[16384];  // 32 KB
  const int t = blockIdx.x;
  gemm_tile<2, 2>(A, Bt, C, 2048, 2048, (t >> 4) * 128, (t & 15) * 128, S);
}

// ---- block-sparse attention (round-3 structure, V^T direct from GEMM) ----
__global__ __launch_bounds__(256) void attn(const _Float16* __restrict__ Qg,
                                            const _Float16* __restrict__ Kg,
                                            const _Float16* __restrict__ Vtg,
                                            _Float16* __restrict__ Og) {
  const int t = blockIdx.x, h = blockIdx.y, b = blockIdx.z;
  __shared__ _Float16 Qs[128 * 128];  // 32 KB
  __shared__ _Float16 Ks[64 * 128];   // 16 KB
  __shared__ _Float16 Vs[128 * 64];   // 16 KB
  const int tid = threadIdx.x;
  const int lane = tid & 63, w = tid >> 6, l16 = lane & 15, quad = lane >> 4;
  const int qbw = 2 * t + (w >> 1);
  const char* QsB = (const char*)Qs;
  const char* KsB = (const char*)Ks;
  const char* VsB = (const char*)Vs;

  #pragma unroll
  for (int p = 0; p < 8; ++p) {
    int o = p * 256 + tid, r = o >> 4, c = o & 15;
    gload_lds16(Qg + (size_t)(b * 2048 + t * 128 + r) * 2048 + h * 128 + ((c ^ (r & 15)) * 8),
                (char*)Qs + o * 16);
  }
  __builtin_amdgcn_s_waitcnt(0);
  __syncthreads();
  f16x8 qf[2][4];
  #pragma unroll
  for (int qc = 0; qc < 2; ++qc)
    #pragma unroll
    for (int ks = 0; ks < 4; ++ks)
      qf[qc][ks] = *(const f16x8*)(QsB + (w * 32 + qc * 16 + l16) * 256 +
                                   (((ks * 4 + quad) ^ l16) * 16));

  const float scale = 0.08838834764831845f;  // 1/sqrt(128)
  float m_[2] = {-1e30f, -1e30f}, l_[2] = {0.f, 0.f};
  f32x4 oacc[8][2];
  #pragma unroll
  for (int dt = 0; dt < 8; ++dt)
    #pragma unroll
    for (int qc = 0; qc < 2; ++qc) oacc[dt][qc] = (f32x4){0.f, 0.f, 0.f, 0.f};

  for (int jj = 0; jj < 6; ++jj) {
    const int j = 2 * t - 2 + jj;
    const int jc = j < 0 ? 0 : (j > 31 ? 31 : j);
    __syncthreads();
    #pragma unroll
    for (int p = 0; p < 4; ++p) {
      int o = p * 256 + tid, r = o >> 4, c = o & 15;
      gload_lds16(Kg + (size_t)(b * 2048 + jc * 64 + r) * 2048 + h * 128 + ((c ^ (r & 15)) * 8),
                  (char*)Ks + o * 16);
    }
    #pragma unroll
    for (int p = 0; p < 4; ++p) {
      int o = p * 256 + tid, d = o >> 3, c = o & 7;
      gload_lds16(Vtg + (size_t)(h * 128 + d) * 4096 + b * 2048 + jc * 64 + ((c ^ (d & 7)) * 8),
                  (char*)Vs + o * 16);
    }
    __builtin_amdgcn_s_waitcnt(0);
    __syncthreads();

    const bool valid = (j >= 0) && (j <= 31) && (j >= qbw - 2) && (j <= qbw + 2);
    if (valid) {
      f32x4 sc[4][2];
      #pragma unroll
      for (int kt = 0; kt < 4; ++kt)
        #pragma unroll
        for (int qc = 0; qc < 2; ++qc) sc[kt][qc] = (f32x4){0.f, 0.f, 0.f, 0.f};
      #pragma unroll
      for (int kt = 0; kt < 4; ++kt)
        #pragma unroll
        for (int ks = 0; ks < 4; ++ks) {
          f16x8 kf = *(const f16x8*)(KsB + (kt * 16 + l16) * 256 + (((ks * 4 + quad) ^ l16) * 16));
          #pragma unroll
          for (int qc = 0; qc < 2; ++qc)
            sc[kt][qc] = __builtin_amdgcn_mfma_f32_16x16x32_f16(kf, qf[qc][ks], sc[kt][qc], 0, 0, 0);
        }
      #pragma unroll
      for (int qc = 0; qc < 2; ++qc) {
        float mj = -1e30f;
        #pragma unroll
        for (int kt = 0; kt < 4; ++kt)
          #pragma unroll
          for (int r = 0; r < 4; ++r) {
            float v = sc[kt][qc][r] * scale;
            sc[kt][qc][r] = v;
            mj = fmaxf(mj, v);
          }
        mj = fmaxf(mj, __shfl_xor(mj, 16));
        mj = fmaxf(mj, __shfl_xor(mj, 32));
        const float mn = fmaxf(m_[qc], mj);
        const float alpha = __expf(m_[qc] - mn);
        float s_ = 0.f;
        #pragma unroll
        for (int kt = 0; kt < 4; ++kt)
          #pragma unroll
          for (int r = 0; r < 4; ++r) {
            float p = __expf(sc[kt][qc][r] - mn);
            sc[kt][qc][r] = p;
            s_ += p;
          }
        s_ += __shfl_xor(s_, 16);
        s_ += __shfl_xor(s_, 32);
        l_[qc] = l_[qc] * alpha + s_;
        m_[qc] = mn;
        #pragma unroll
        for (int dt = 0; dt < 8; ++dt) oacc[dt][qc] *= alpha;
      }
      #pragma unroll
      for (int kt = 0; kt < 4; ++kt) {
        f16x4 pb[2];
        #pragma unroll
        for (int qc = 0; qc < 2; ++qc)
          pb[qc] = (f16x4){ (_Float16)sc[kt][qc][0], (_Float16)sc[kt][qc][1],
                            (_Float16)sc[kt][qc][2], (_Float16)sc[kt][qc][3] };
        #pragma unroll
        for (int dt = 0; dt < 8; ++dt) {
          f16x4 vv = *(const f16x4*)(VsB + (dt * 16 + l16) * 128 +
                                     (((2 * kt + (quad >> 1)) ^ (l16 & 7)) * 16) + (quad & 1) * 8);
          #pragma unroll
          for (int qc = 0; qc < 2; ++qc)
            oacc[dt][qc] = __builtin_amdgcn_mfma_f32_16x16x16f16(vv, pb[qc], oacc[dt][qc], 0, 0, 0);
        }
      }
    }
  }

  #pragma unroll
  for (int qc = 0; qc < 2; ++qc) {
    const float pinv = 1.0f / l_[qc];
    const size_t orow = (size_t)(b * 2048 + t * 128 + w * 32 + qc * 16 + l16);
    #pragma unroll
    for (int dt = 0; dt < 8; ++dt) {
      f16x4 ov = { (_Float16)(oacc[dt][qc][0] * pinv), (_Float16)(oacc[dt][qc][1] * pinv),
                   (_Float16)(oacc[dt][qc][2] * pinv), (_Float16)(oacc[dt][qc][3] * pinv) };
      *(f16x4*)(Og + orow * 2048 + h * 128 + dt * 16 + quad * 4) = ov;
    }
  }
}

extern "C" void kernel_launch(void* const* d_in, const int* in_sizes, int n_in,
                              void* d_out, int out_size, void* d_ws, size_t ws_size,
                              hipStream_t stream) {
  const float* Hs = (const float*)d_in[0];
  const float* Wq = (const float*)d_in[1];
  const float* Wk = (const float*)d_in[2];
  const float* Wv = (const float*)d_in[3];
  const float* Wo = (const float*)d_in[4];
  _Float16* Hb  = (_Float16*)d_ws;          // H cast  [4096][2048]
  _Float16* Wt  = Hb  + 8388608;            // Wq/Wk/Wv/Wo^T  4 x [2048][2048]
  _Float16* Qb  = Wt  + 16777216;           // Q  [b*2048+s][h*128+d]
  _Float16* Kb  = Qb  + 8388608;            // K  (= Qb + zsC, written by qkvv z=1)
  _Float16* Vtb = Kb  + 8388608;            // V^T [h*128+d][b*2048+s]
  _Float16* Ob  = Vtb + 8388608;            // attn out [b*2048+s][h*128+d]
  float* out = (float*)d_out;
  (void)Kb;

  prep<<<12288, 256, 0, stream>>>(Hs, Wq, Wk, Wv, Wo, Hb, Wt);
  qkvv<<<768, 256, 0, stream>>>(Hb, Wt, Qb, Vtb);
  attn<<<dim3(16, 16, 2), 256, 0, stream>>>(Qb, Kb, Vtb, Ob);
  gemm_wo<<<512, 256, 0, stream>>>(Ob, Wt + (size_t)3 * 4194304, out);
}